// Round 5
// baseline (72346.967 us; speedup 1.0000x reference)
//
#include <hip/hip_runtime.h>
#include <math.h>

#define NB 16384
#define DIN 768

// ---------------- small kernels ----------------

__global__ void k_zero2(float* a, float* b) {
    if (threadIdx.x == 0) { *a = 0.f; *b = 0.f; }
}

__global__ void k_norm(const float* __restrict__ x, const float* __restrict__ m,
                       const float* __restrict__ s, float* __restrict__ xn) {
    int i = blockIdx.x * 256 + threadIdx.x;          // 16384*768 total
    int j = i % DIN;
    xn[i] = (x[i] - m[j]) / s[j];
}

// one 64-lane wave per codebook row (4 rows / 256-thread block)
__global__ void k_cbnorm(const float* __restrict__ cb, float* __restrict__ cbn) {
    int row = blockIdx.x * 4 + (threadIdx.x >> 6);
    int lane = threadIdx.x & 63;
    const float* p = cb + (size_t)row * 128;
    float v0 = p[lane], v1 = p[lane + 64];
    float s = v0 * v0 + v1 * v1;
    #pragma unroll
    for (int m = 32; m >= 1; m >>= 1) s += __shfl_xor(s, m, 64);
    if (lane == 0) cbn[row] = s;
}

// ---------------- fused Linear + ReLU + RMSNorm ----------------
// block = 32 rows x N cols; threads (tx=32, ty=8); per-thread 4 rows x N/32 cols
template <int N>
__global__ __launch_bounds__(256, 2) void k_lin_relu_rms(
    const float* __restrict__ A, const float* __restrict__ W,
    const float* __restrict__ bias, const float* __restrict__ g,
    float* __restrict__ out, int K) {
    constexpr int CJ = N / 32;
    __shared__ float Asub[32][17];
    __shared__ float Wsub[16][N];
    __shared__ float rsums[32];
    const int tid = threadIdx.x;
    const int tx = tid & 31, ty = tid >> 5;
    const int row0 = blockIdx.x * 32;

    float acc[4][CJ];
    #pragma unroll
    for (int r = 0; r < 4; r++)
        #pragma unroll
        for (int j = 0; j < CJ; j++) acc[r][j] = 0.f;

    for (int k0 = 0; k0 < K; k0 += 16) {
        for (int e = tid; e < 512; e += 256) {
            int r = e >> 4, kk = e & 15;
            Asub[r][kk] = A[(size_t)(row0 + r) * K + k0 + kk];
        }
        constexpr int NW4 = 16 * N / 4;
        for (int e = tid; e < NW4; e += 256) {
            int kk = e / (N / 4), c4 = e % (N / 4);
            *(float4*)&Wsub[kk][c4 * 4] = *(const float4*)&W[(size_t)(k0 + kk) * N + c4 * 4];
        }
        __syncthreads();
        #pragma unroll
        for (int kk = 0; kk < 16; kk++) {
            float a[4];
            #pragma unroll
            for (int r = 0; r < 4; r++) a[r] = Asub[ty * 4 + r][kk];
            #pragma unroll
            for (int j = 0; j < CJ; j++) {
                float w = Wsub[kk][tx + 32 * j];
                #pragma unroll
                for (int r = 0; r < 4; r++) acc[r][j] = fmaf(a[r], w, acc[r][j]);
            }
        }
        __syncthreads();
    }
    // bias + relu + per-row sum of squares
    float ss[4] = {0.f, 0.f, 0.f, 0.f};
    #pragma unroll
    for (int j = 0; j < CJ; j++) {
        float bb = bias[tx + 32 * j];
        #pragma unroll
        for (int r = 0; r < 4; r++) {
            float v = acc[r][j] + bb;
            v = v > 0.f ? v : 0.f;
            acc[r][j] = v;
            ss[r] = fmaf(v, v, ss[r]);
        }
    }
    #pragma unroll
    for (int m = 1; m < 32; m <<= 1)
        #pragma unroll
        for (int r = 0; r < 4; r++) ss[r] += __shfl_xor(ss[r], m, 64);
    if (tx == 0)
        #pragma unroll
        for (int r = 0; r < 4; r++) rsums[ty * 4 + r] = ss[r];
    __syncthreads();
    constexpr float invN = 1.0f / (float)N;
    #pragma unroll
    for (int r = 0; r < 4; r++) {
        float scale = 1.0f / sqrtf(rsums[ty * 4 + r] * invN + 1e-6f);
        #pragma unroll
        for (int j = 0; j < CJ; j++) {
            int col = tx + 32 * j;
            out[(size_t)(row0 + ty * 4 + r) * N + col] = acc[r][j] * scale * g[col];
        }
    }
}

// ---------------- VQ: exact fp32 score + partial argmin (v3) ----------------
// grid = (NB/64 row-blocks, 2 code-strips of 4096). block = 256 threads (4 waves):
// tx = tid&7 (codes), ty = tid>>3 (0..31, rows). Per-thread 2 rows x 4 codes.
// Rows: {ty, ty+32}. Within a wave ty spans 8 consecutive values, so each LDS
// fragment-read instruction touches 8 CONSECUTIVE rows; with row stride 132
// (== 4 mod 8) banks are 4*ty + 4*k4: all 8 quads distinct -> conflict-free.
// Same for E reads over tx. All row starts 528 B -> 16 B aligned.
// R tile 64x128 resident in LDS; E staged 32 codes x full K, double-buffered,
// one __syncthreads per chunk. LDS = 2 x 33.8 KB = 67.6 KB -> 2 blocks/CU.
// s_k = ||E_k||^2 - 2*r.E_k (row-constant ||r||^2 dropped; argmin-equivalent)
#define CSTRIP 4096
#define NCHUNK (CSTRIP / 32)
__global__ __launch_bounds__(256, 2) void k_vq_argmin(
    const float* __restrict__ R, const float* __restrict__ E,
    const float* __restrict__ cbn,
    float* __restrict__ pbest, int* __restrict__ pidx) {
    __shared__ float Rs[64][132];
    __shared__ float Es[2][32][132];
    const int tid = threadIdx.x;
    const int tx = tid & 7;
    const int ty = tid >> 3;                 // 0..31
    const int row0 = blockIdx.x * 64;
    const int cbase = blockIdx.y * CSTRIP;

    // stage Rs: 64x128 = 2048 float4, 8 per thread (coalesced, aligned)
    for (int f = tid; f < 2048; f += 256) {
        int r = f >> 5, k4 = f & 31;
        *(float4*)&Rs[r][k4 * 4] = *(const float4*)&R[(size_t)(row0 + r) * 128 + k4 * 4];
    }
    // prefetch chunk 0 (32 codes x 128 k = 1024 float4, 4 per thread)
    float4 st[4];
    #pragma unroll
    for (int t = 0; t < 4; t++) {
        int f = tid + 256 * t;
        int c = f >> 5, k4 = f & 31;
        st[t] = *(const float4*)&E[(size_t)(cbase + c) * 128 + k4 * 4];
    }
    #pragma unroll
    for (int t = 0; t < 4; t++) {
        int f = tid + 256 * t;
        int c = f >> 5, k4 = f & 31;
        *(float4*)&Es[0][c][k4 * 4] = st[t];
    }
    __syncthreads();

    float best[2];
    int bidx[2];
    best[0] = 3.402823466e+38f; best[1] = 3.402823466e+38f;
    bidx[0] = 0; bidx[1] = 0;

    for (int cc = 0; cc < NCHUNK; cc++) {
        const int cur = cc & 1;
        const bool more = (cc + 1 < NCHUNK);
        // issue next-chunk global loads early (latency hidden by compute)
        if (more) {
            #pragma unroll
            for (int t = 0; t < 4; t++) {
                int f = tid + 256 * t;
                int c = f >> 5, k4 = f & 31;
                st[t] = *(const float4*)&E[(size_t)(cbase + (cc + 1) * 32 + c) * 128 + k4 * 4];
            }
        }
        float4 acc4[2][4];
        #pragma unroll
        for (int r = 0; r < 2; r++)
            #pragma unroll
            for (int j = 0; j < 4; j++) { acc4[r][j].x = 0.f; acc4[r][j].y = 0.f; acc4[r][j].z = 0.f; acc4[r][j].w = 0.f; }

        #pragma unroll
        for (int k4 = 0; k4 < 32; k4++) {
            float4 a0 = *(const float4*)&Rs[ty][k4 * 4];
            float4 a1 = *(const float4*)&Rs[ty + 32][k4 * 4];
            #pragma unroll
            for (int j = 0; j < 4; j++) {
                float4 e = *(const float4*)&Es[cur][tx + 8 * j][k4 * 4];
                acc4[0][j].x = fmaf(a0.x, e.x, acc4[0][j].x);
                acc4[0][j].y = fmaf(a0.y, e.y, acc4[0][j].y);
                acc4[0][j].z = fmaf(a0.z, e.z, acc4[0][j].z);
                acc4[0][j].w = fmaf(a0.w, e.w, acc4[0][j].w);
                acc4[1][j].x = fmaf(a1.x, e.x, acc4[1][j].x);
                acc4[1][j].y = fmaf(a1.y, e.y, acc4[1][j].y);
                acc4[1][j].z = fmaf(a1.z, e.z, acc4[1][j].z);
                acc4[1][j].w = fmaf(a1.w, e.w, acc4[1][j].w);
            }
        }
        // epilogue: horizontal add + running argmin
        // per-thread code order ascending across (cc, j) -> strict < keeps first
        #pragma unroll
        for (int j = 0; j < 4; j++) {
            int c = cbase + cc * 32 + tx + 8 * j;
            float cn = cbn[c];
            #pragma unroll
            for (int r = 0; r < 2; r++) {
                float h = (acc4[r][j].x + acc4[r][j].y) + (acc4[r][j].z + acc4[r][j].w);
                float s = fmaf(-2.f, h, cn);
                if (s < best[r]) { best[r] = s; bidx[r] = c; }
            }
        }
        // write next chunk into the other buffer (its readers finished at the
        // sync that ended iteration cc-1), then one sync to publish
        if (more) {
            #pragma unroll
            for (int t = 0; t < 4; t++) {
                int f = tid + 256 * t;
                int c = f >> 5, k4 = f & 31;
                *(float4*)&Es[1 - cur][c][k4 * 4] = st[t];
            }
        }
        __syncthreads();
    }
    // reduce across the 8 tx lanes; tie -> smaller index (numpy first-occurrence)
    #pragma unroll
    for (int mask = 1; mask < 8; mask <<= 1) {
        #pragma unroll
        for (int r = 0; r < 2; r++) {
            float ob = __shfl_xor(best[r], mask, 64);
            int oi = __shfl_xor(bidx[r], mask, 64);
            if (ob < best[r] || (ob == best[r] && oi < bidx[r])) { best[r] = ob; bidx[r] = oi; }
        }
    }
    if (tx == 0) {
        #pragma unroll
        for (int r = 0; r < 2; r++) {
            int row = row0 + ty + 32 * r;
            pbest[(size_t)blockIdx.y * NB + row] = best[r];
            pidx[(size_t)blockIdx.y * NB + row] = bidx[r];
        }
    }
}

// merge the 2 strip-partials; tie -> smaller index
__global__ void k_vq_reduce(const float* __restrict__ pbest, const int* __restrict__ pidx,
                            int* __restrict__ idx_out, float* __restrict__ ids_f) {
    int row = blockIdx.x * 256 + threadIdx.x;
    float b = pbest[row];
    int bi = pidx[row];
    #pragma unroll
    for (int s = 1; s < 2; s++) {
        float ob = pbest[(size_t)s * NB + row];
        int oi = pidx[(size_t)s * NB + row];
        if (ob < b || (ob == b && oi < bi)) { b = ob; bi = oi; }
    }
    idx_out[row] = bi;
    ids_f[(size_t)row * 4] = (float)bi;
}

// gather + residual update + qsum + vq_loss partial
__global__ void k_vq_update(const float* __restrict__ Rin, const int* __restrict__ idx,
                            const float* __restrict__ E, float* __restrict__ Rout,
                            float* __restrict__ qsum, float* __restrict__ vq_acc,
                            int firstq) {
    __shared__ float ps[4];
    int i = blockIdx.x * 256 + threadIdx.x;   // NB*128 total
    int row = i >> 7, d = i & 127;
    float e = E[(size_t)idx[row] * 128 + d];
    float rv = Rin[i] - e;
    Rout[i] = rv;
    qsum[i] = firstq ? e : (qsum[i] + e);
    float p = rv * rv;
    #pragma unroll
    for (int m = 1; m < 64; m <<= 1) p += __shfl_xor(p, m, 64);
    int lane = threadIdx.x & 63, w = threadIdx.x >> 6;
    if (lane == 0) ps[w] = p;
    __syncthreads();
    if (threadIdx.x == 0)
        atomicAdd(vq_acc, (ps[0] + ps[1] + ps[2] + ps[3]) * (1.25f / ((float)NB * 128.f)));
}

// ---------------- final Linear (512->768) + recon loss ----------------
// 64x64 tile; threads (16,16); micro 4x4. Reads xn from rec[], overwrites with recon.
__global__ __launch_bounds__(256, 2) void k_dec2(
    const float* __restrict__ A, const float* __restrict__ W,
    const float* __restrict__ bias, float* __restrict__ rec,
    float* __restrict__ loss_acc) {
    __shared__ float Asub[64][17];
    __shared__ float Wsub[16][64];
    __shared__ float red[4];
    const int tid = threadIdx.x;
    const int tx = tid & 15, ty = tid >> 4;
    const int row0 = blockIdx.x * 64, col0 = blockIdx.y * 64;
    float acc[4][4];
    #pragma unroll
    for (int r = 0; r < 4; r++)
        #pragma unroll
        for (int j = 0; j < 4; j++) acc[r][j] = 0.f;

    for (int k0 = 0; k0 < 512; k0 += 16) {
        for (int e = tid; e < 1024; e += 256) {
            int r = e >> 4, kk = e & 15;
            Asub[r][kk] = A[(size_t)(row0 + r) * 512 + k0 + kk];
        }
        {
            int kk = tid >> 4, c = tid & 15;
            *(float4*)&Wsub[kk][c * 4] = *(const float4*)&W[(size_t)(k0 + kk) * DIN + col0 + c * 4];
        }
        __syncthreads();
        #pragma unroll
        for (int kk = 0; kk < 16; kk++) {
            float a[4], w[4];
            #pragma unroll
            for (int r = 0; r < 4; r++) a[r] = Asub[ty * 4 + r][kk];
            #pragma unroll
            for (int j = 0; j < 4; j++) w[j] = Wsub[kk][tx + 16 * j];
            #pragma unroll
            for (int r = 0; r < 4; r++)
                #pragma unroll
                for (int j = 0; j < 4; j++) acc[r][j] = fmaf(a[r], w[j], acc[r][j]);
        }
        __syncthreads();
    }
    float lsum = 0.f;
    #pragma unroll
    for (int j = 0; j < 4; j++) {
        int col = col0 + tx + 16 * j;
        float bb = bias[col];
        #pragma unroll
        for (int r = 0; r < 4; r++) {
            int row = row0 + ty * 4 + r;
            float v = acc[r][j] + bb;
            size_t o = (size_t)row * DIN + col;
            float e = v - rec[o];     // rec holds xn here
            lsum = fmaf(e, e, lsum);
            rec[o] = v;
        }
    }
    #pragma unroll
    for (int m = 1; m < 64; m <<= 1) lsum += __shfl_xor(lsum, m, 64);
    int lane = tid & 63, w = tid >> 6;
    if (lane == 0) red[w] = lsum;
    __syncthreads();
    if (tid == 0)
        atomicAdd(loss_acc, (red[0] + red[1] + red[2] + red[3]) * (1.0f / ((float)NB * (float)DIN)));
}

// ---------------- launch ----------------

extern "C" void kernel_launch(void* const* d_in, const int* in_sizes, int n_in,
                              void* d_out, int out_size, void* d_ws, size_t ws_size,
                              hipStream_t stream) {
    (void)in_sizes; (void)n_in; (void)out_size; (void)ws_size;
    const float* x        = (const float*)d_in[0];
    const float* emb_mean = (const float*)d_in[1];
    const float* emb_std  = (const float*)d_in[2];
    const float* enc_w0 = (const float*)d_in[3];
    const float* enc_b0 = (const float*)d_in[4];
    const float* enc_g0 = (const float*)d_in[5];
    const float* enc_w1 = (const float*)d_in[6];
    const float* enc_b1 = (const float*)d_in[7];
    const float* enc_g1 = (const float*)d_in[8];
    const float* enc_w2 = (const float*)d_in[9];
    const float* enc_b2 = (const float*)d_in[10];
    const float* enc_g2 = (const float*)d_in[11];
    const float* cb     = (const float*)d_in[12];
    const float* dec_w0 = (const float*)d_in[13];
    const float* dec_b0 = (const float*)d_in[14];
    const float* dec_g0 = (const float*)d_in[15];
    const float* dec_w1 = (const float*)d_in[16];
    const float* dec_b1 = (const float*)d_in[17];
    const float* dec_g1 = (const float*)d_in[18];
    const float* dec_w2 = (const float*)d_in[19];
    const float* dec_b2 = (const float*)d_in[20];

    float* out   = (float*)d_out;
    float* xn    = out;                        // recon region doubles as xn scratch
    float* ids_f = out + (size_t)NB * DIN;     // 12582912
    float* rl    = out + (size_t)NB * DIN + (size_t)NB * 4;      // 12648448
    float* vl    = rl + 1;

    float* ws   = (float*)d_ws;
    float* h0   = ws;                           // 16384*512
    float* h1   = h0 + (size_t)NB * 512;        // 16384*256
    float* h2   = h1 + (size_t)NB * 256;        // 16384*128
    float* rbuf = h2 + (size_t)NB * 128;        // 16384*128
    float* qsum = rbuf + (size_t)NB * 128;      // 16384*128
    float* cbn  = qsum + (size_t)NB * 128;      // 4*8192
    int*   idxb = (int*)(cbn + 4 * 8192);       // 16384

    // strip-partial argmin buffers live in h0 (free between encoder and decoder)
    float* pbest = h0;                          // 2*16384 floats
    int*   pidx  = (int*)(h0 + 2 * (size_t)NB); // 2*16384 ints

    k_zero2<<<1, 64, 0, stream>>>(rl, vl);
    k_norm<<<(NB * DIN) / 256, 256, 0, stream>>>(x, emb_mean, emb_std, xn);
    k_cbnorm<<<(4 * 8192) / 4, 256, 0, stream>>>(cb, cbn);

    k_lin_relu_rms<512><<<NB / 32, 256, 0, stream>>>(xn, enc_w0, enc_b0, enc_g0, h0, 768);
    k_lin_relu_rms<256><<<NB / 32, 256, 0, stream>>>(h0, enc_w1, enc_b1, enc_g1, h1, 512);
    k_lin_relu_rms<128><<<NB / 32, 256, 0, stream>>>(h1, enc_w2, enc_b2, enc_g2, h2, 256);

    for (int q = 0; q < 4; q++) {
        const float* R = (q == 0) ? h2 : rbuf;
        const float* Eq = cb + (size_t)q * 8192 * 128;
        dim3 gq(NB / 64, 2);
        k_vq_argmin<<<gq, 256, 0, stream>>>(R, Eq, cbn + q * 8192, pbest, pidx);
        k_vq_reduce<<<NB / 256, 256, 0, stream>>>(pbest, pidx, idxb, ids_f + q);
        k_vq_update<<<(NB * 128) / 256, 256, 0, stream>>>(R, idxb, Eq, rbuf, qsum, vl, q == 0 ? 1 : 0);
    }

    k_lin_relu_rms<256><<<NB / 32, 256, 0, stream>>>(qsum, dec_w0, dec_b0, dec_g0, h1, 128);
    k_lin_relu_rms<512><<<NB / 32, 256, 0, stream>>>(h1, dec_w1, dec_b1, dec_g1, h0, 256);

    dim3 g2(NB / 64, DIN / 64);
    k_dec2<<<g2, 256, 0, stream>>>(h0, dec_w2, dec_b2, xn, rl);
}

// Round 6
// 3257.802 us; speedup vs baseline: 22.2073x; 22.2073x over previous
//
#include <hip/hip_runtime.h>
#include <math.h>

#define NB 16384
#define DIN 768

// ---------------- small kernels ----------------

__global__ void k_zero2(float* a, float* b) {
    if (threadIdx.x == 0) { *a = 0.f; *b = 0.f; }
}

__global__ void k_norm(const float* __restrict__ x, const float* __restrict__ m,
                       const float* __restrict__ s, float* __restrict__ xn) {
    int i = blockIdx.x * 256 + threadIdx.x;          // 16384*768 total
    int j = i % DIN;
    xn[i] = (x[i] - m[j]) / s[j];
}

// one 64-lane wave per codebook row (4 rows / 256-thread block)
__global__ void k_cbnorm(const float* __restrict__ cb, float* __restrict__ cbn) {
    int row = blockIdx.x * 4 + (threadIdx.x >> 6);
    int lane = threadIdx.x & 63;
    const float* p = cb + (size_t)row * 128;
    float v0 = p[lane], v1 = p[lane + 64];
    float s = v0 * v0 + v1 * v1;
    #pragma unroll
    for (int m = 32; m >= 1; m >>= 1) s += __shfl_xor(s, m, 64);
    if (lane == 0) cbn[row] = s;
}

// ---------------- fused Linear + ReLU + RMSNorm ----------------
// block = 32 rows x N cols; threads (tx=32, ty=8); per-thread 4 rows x N/32 cols
template <int N>
__global__ __launch_bounds__(256, 2) void k_lin_relu_rms(
    const float* __restrict__ A, const float* __restrict__ W,
    const float* __restrict__ bias, const float* __restrict__ g,
    float* __restrict__ out, int K) {
    constexpr int CJ = N / 32;
    __shared__ float Asub[32][17];
    __shared__ float Wsub[16][N];
    __shared__ float rsums[32];
    const int tid = threadIdx.x;
    const int tx = tid & 31, ty = tid >> 5;
    const int row0 = blockIdx.x * 32;

    float acc[4][CJ];
    #pragma unroll
    for (int r = 0; r < 4; r++)
        #pragma unroll
        for (int j = 0; j < CJ; j++) acc[r][j] = 0.f;

    for (int k0 = 0; k0 < K; k0 += 16) {
        for (int e = tid; e < 512; e += 256) {
            int r = e >> 4, kk = e & 15;
            Asub[r][kk] = A[(size_t)(row0 + r) * K + k0 + kk];
        }
        constexpr int NW4 = 16 * N / 4;
        for (int e = tid; e < NW4; e += 256) {
            int kk = e / (N / 4), c4 = e % (N / 4);
            *(float4*)&Wsub[kk][c4 * 4] = *(const float4*)&W[(size_t)(k0 + kk) * N + c4 * 4];
        }
        __syncthreads();
        #pragma unroll
        for (int kk = 0; kk < 16; kk++) {
            float a[4];
            #pragma unroll
            for (int r = 0; r < 4; r++) a[r] = Asub[ty * 4 + r][kk];
            #pragma unroll
            for (int j = 0; j < CJ; j++) {
                float w = Wsub[kk][tx + 32 * j];
                #pragma unroll
                for (int r = 0; r < 4; r++) acc[r][j] = fmaf(a[r], w, acc[r][j]);
            }
        }
        __syncthreads();
    }
    // bias + relu + per-row sum of squares
    float ss[4] = {0.f, 0.f, 0.f, 0.f};
    #pragma unroll
    for (int j = 0; j < CJ; j++) {
        float bb = bias[tx + 32 * j];
        #pragma unroll
        for (int r = 0; r < 4; r++) {
            float v = acc[r][j] + bb;
            v = v > 0.f ? v : 0.f;
            acc[r][j] = v;
            ss[r] = fmaf(v, v, ss[r]);
        }
    }
    #pragma unroll
    for (int m = 1; m < 32; m <<= 1)
        #pragma unroll
        for (int r = 0; r < 4; r++) ss[r] += __shfl_xor(ss[r], m, 64);
    if (tx == 0)
        #pragma unroll
        for (int r = 0; r < 4; r++) rsums[ty * 4 + r] = ss[r];
    __syncthreads();
    constexpr float invN = 1.0f / (float)N;
    #pragma unroll
    for (int r = 0; r < 4; r++) {
        float scale = 1.0f / sqrtf(rsums[ty * 4 + r] * invN + 1e-6f);
        #pragma unroll
        for (int j = 0; j < CJ; j++) {
            int col = tx + 32 * j;
            out[(size_t)(row0 + ty * 4 + r) * N + col] = acc[r][j] * scale * g[col];
        }
    }
}

// ---------------- VQ: exact fp32 score + partial argmin (v4) ----------------
// Round-1 proven skeleton (scalar LDS reads, no VGPR cap) + occupancy + fatter tile.
// grid = (NB/64, 2 strips of 4096 codes); block = 256 threads (4 waves).
// tx = tid&31 (codes), ty = tid>>5 (row group); micro-tile 8 rows x 8 codes.
// Rs[64][132] staged once (float4 writes, 16B aligned); Es[256][33] staged per
// 32-k chunk (scalar writes, <=2-way banks). Inner loop: 8 R-reads (2-addr
// broadcast) + 8 E-reads (stride 33 -> 32 distinct banks) per 64 FMAs.
// NO second __launch_bounds__ arg: VGPR cap stays 512 -> no spill (R5 lesson).
// s_k = ||E_k||^2 - 2*r.E_k (row-constant ||r||^2 dropped; argmin-equivalent)
#define CSTRIP 4096
__global__ __launch_bounds__(256) void k_vq_argmin(
    const float* __restrict__ R, const float* __restrict__ E,
    const float* __restrict__ cbn,
    float* __restrict__ pbest, int* __restrict__ pidx) {
    __shared__ float Rs[64][132];
    __shared__ float Es[256][33];
    const int tid = threadIdx.x;
    const int tx = tid & 31;
    const int ty = tid >> 5;                 // 0..7
    const int row0 = blockIdx.x * 64;
    const int cbase = blockIdx.y * CSTRIP;

    // stage Rs 64x128 once: 2048 float4, 8 per thread, 16B-aligned rows
    for (int f = tid; f < 2048; f += 256) {
        int r = f >> 5, k4 = f & 31;
        *(float4*)&Rs[r][k4 * 4] = *(const float4*)&R[(size_t)(row0 + r) * 128 + k4 * 4];
    }

    float best[8];
    int bidx[8];
    #pragma unroll
    for (int m = 0; m < 8; m++) { best[m] = 3.402823466e+38f; bidx[m] = 0; }

    for (int ct = 0; ct < CSTRIP / 256; ct++) {        // 16 code tiles of 256
        const int c0 = cbase + ct * 256;
        float acc[8][8];
        #pragma unroll
        for (int r = 0; r < 8; r++)
            #pragma unroll
            for (int j = 0; j < 8; j++) acc[r][j] = 0.f;

        for (int k0 = 0; k0 < 128; k0 += 32) {
            __syncthreads();   // previous chunk's readers done (covers Rs stage too)
            // stage Es chunk [256 codes][32 k]: 2048 float4, 8 per thread
            for (int t = 0; t < 8; t++) {
                int f = tid + 256 * t;
                int c = f >> 3, k4 = f & 7;
                float4 v = *(const float4*)&E[(size_t)(c0 + c) * 128 + k0 + k4 * 4];
                int kb = k4 * 4;
                Es[c][kb] = v.x; Es[c][kb + 1] = v.y; Es[c][kb + 2] = v.z; Es[c][kb + 3] = v.w;
            }
            __syncthreads();
            #pragma unroll 4
            for (int k = 0; k < 32; k++) {
                float a[8], e[8];
                #pragma unroll
                for (int r = 0; r < 8; r++) a[r] = Rs[ty * 8 + r][k0 + k];
                #pragma unroll
                for (int j = 0; j < 8; j++) e[j] = Es[tx + 32 * j][k];
                #pragma unroll
                for (int r = 0; r < 8; r++)
                    #pragma unroll
                    for (int j = 0; j < 8; j++) acc[r][j] = fmaf(a[r], e[j], acc[r][j]);
            }
        }
        // running argmin; per-thread code order ascending -> strict < keeps first
        #pragma unroll
        for (int j = 0; j < 8; j++) {
            int c = c0 + tx + 32 * j;
            float cn = cbn[c];
            #pragma unroll
            for (int r = 0; r < 8; r++) {
                float s = fmaf(-2.f, acc[r][j], cn);
                if (s < best[r]) { best[r] = s; bidx[r] = c; }
            }
        }
    }
    // reduce across the 32 tx lanes (xor masks stay within same-ty half-wave);
    // tie -> smaller index (numpy first-occurrence)
    #pragma unroll
    for (int mask = 1; mask < 32; mask <<= 1) {
        #pragma unroll
        for (int r = 0; r < 8; r++) {
            float ob = __shfl_xor(best[r], mask, 64);
            int oi = __shfl_xor(bidx[r], mask, 64);
            if (ob < best[r] || (ob == best[r] && oi < bidx[r])) { best[r] = ob; bidx[r] = oi; }
        }
    }
    if (tx == 0) {
        #pragma unroll
        for (int r = 0; r < 8; r++) {
            int row = row0 + ty * 8 + r;
            pbest[(size_t)blockIdx.y * NB + row] = best[r];
            pidx[(size_t)blockIdx.y * NB + row] = bidx[r];
        }
    }
}

// merge the 2 strip-partials; tie -> smaller index
__global__ void k_vq_reduce(const float* __restrict__ pbest, const int* __restrict__ pidx,
                            int* __restrict__ idx_out, float* __restrict__ ids_f) {
    int row = blockIdx.x * 256 + threadIdx.x;
    float b = pbest[row];
    int bi = pidx[row];
    #pragma unroll
    for (int s = 1; s < 2; s++) {
        float ob = pbest[(size_t)s * NB + row];
        int oi = pidx[(size_t)s * NB + row];
        if (ob < b || (ob == b && oi < bi)) { b = ob; bi = oi; }
    }
    idx_out[row] = bi;
    ids_f[(size_t)row * 4] = (float)bi;
}

// gather + residual update + qsum + vq_loss partial
__global__ void k_vq_update(const float* __restrict__ Rin, const int* __restrict__ idx,
                            const float* __restrict__ E, float* __restrict__ Rout,
                            float* __restrict__ qsum, float* __restrict__ vq_acc,
                            int firstq) {
    __shared__ float ps[4];
    int i = blockIdx.x * 256 + threadIdx.x;   // NB*128 total
    int row = i >> 7, d = i & 127;
    float e = E[(size_t)idx[row] * 128 + d];
    float rv = Rin[i] - e;
    Rout[i] = rv;
    qsum[i] = firstq ? e : (qsum[i] + e);
    float p = rv * rv;
    #pragma unroll
    for (int m = 1; m < 64; m <<= 1) p += __shfl_xor(p, m, 64);
    int lane = threadIdx.x & 63, w = threadIdx.x >> 6;
    if (lane == 0) ps[w] = p;
    __syncthreads();
    if (threadIdx.x == 0)
        atomicAdd(vq_acc, (ps[0] + ps[1] + ps[2] + ps[3]) * (1.25f / ((float)NB * 128.f)));
}

// ---------------- final Linear (512->768) + recon loss ----------------
// 64x64 tile; threads (16,16); micro 4x4. Reads xn from rec[], overwrites with recon.
__global__ __launch_bounds__(256, 2) void k_dec2(
    const float* __restrict__ A, const float* __restrict__ W,
    const float* __restrict__ bias, float* __restrict__ rec,
    float* __restrict__ loss_acc) {
    __shared__ float Asub[64][17];
    __shared__ float Wsub[16][64];
    __shared__ float red[4];
    const int tid = threadIdx.x;
    const int tx = tid & 15, ty = tid >> 4;
    const int row0 = blockIdx.x * 64, col0 = blockIdx.y * 64;
    float acc[4][4];
    #pragma unroll
    for (int r = 0; r < 4; r++)
        #pragma unroll
        for (int j = 0; j < 4; j++) acc[r][j] = 0.f;

    for (int k0 = 0; k0 < 512; k0 += 16) {
        for (int e = tid; e < 1024; e += 256) {
            int r = e >> 4, kk = e & 15;
            Asub[r][kk] = A[(size_t)(row0 + r) * 512 + k0 + kk];
        }
        {
            int kk = tid >> 4, c = tid & 15;
            *(float4*)&Wsub[kk][c * 4] = *(const float4*)&W[(size_t)(k0 + kk) * DIN + col0 + c * 4];
        }
        __syncthreads();
        #pragma unroll
        for (int kk = 0; kk < 16; kk++) {
            float a[4], w[4];
            #pragma unroll
            for (int r = 0; r < 4; r++) a[r] = Asub[ty * 4 + r][kk];
            #pragma unroll
            for (int j = 0; j < 4; j++) w[j] = Wsub[kk][tx + 16 * j];
            #pragma unroll
            for (int r = 0; r < 4; r++)
                #pragma unroll
                for (int j = 0; j < 4; j++) acc[r][j] = fmaf(a[r], w[j], acc[r][j]);
        }
        __syncthreads();
    }
    float lsum = 0.f;
    #pragma unroll
    for (int j = 0; j < 4; j++) {
        int col = col0 + tx + 16 * j;
        float bb = bias[col];
        #pragma unroll
        for (int r = 0; r < 4; r++) {
            int row = row0 + ty * 4 + r;
            float v = acc[r][j] + bb;
            size_t o = (size_t)row * DIN + col;
            float e = v - rec[o];     // rec holds xn here
            lsum = fmaf(e, e, lsum);
            rec[o] = v;
        }
    }
    #pragma unroll
    for (int m = 1; m < 64; m <<= 1) lsum += __shfl_xor(lsum, m, 64);
    int lane = tid & 63, w = tid >> 6;
    if (lane == 0) red[w] = lsum;
    __syncthreads();
    if (tid == 0)
        atomicAdd(loss_acc, (red[0] + red[1] + red[2] + red[3]) * (1.0f / ((float)NB * (float)DIN)));
}

// ---------------- launch ----------------

extern "C" void kernel_launch(void* const* d_in, const int* in_sizes, int n_in,
                              void* d_out, int out_size, void* d_ws, size_t ws_size,
                              hipStream_t stream) {
    (void)in_sizes; (void)n_in; (void)out_size; (void)ws_size;
    const float* x        = (const float*)d_in[0];
    const float* emb_mean = (const float*)d_in[1];
    const float* emb_std  = (const float*)d_in[2];
    const float* enc_w0 = (const float*)d_in[3];
    const float* enc_b0 = (const float*)d_in[4];
    const float* enc_g0 = (const float*)d_in[5];
    const float* enc_w1 = (const float*)d_in[6];
    const float* enc_b1 = (const float*)d_in[7];
    const float* enc_g1 = (const float*)d_in[8];
    const float* enc_w2 = (const float*)d_in[9];
    const float* enc_b2 = (const float*)d_in[10];
    const float* enc_g2 = (const float*)d_in[11];
    const float* cb     = (const float*)d_in[12];
    const float* dec_w0 = (const float*)d_in[13];
    const float* dec_b0 = (const float*)d_in[14];
    const float* dec_g0 = (const float*)d_in[15];
    const float* dec_w1 = (const float*)d_in[16];
    const float* dec_b1 = (const float*)d_in[17];
    const float* dec_g1 = (const float*)d_in[18];
    const float* dec_w2 = (const float*)d_in[19];
    const float* dec_b2 = (const float*)d_in[20];

    float* out   = (float*)d_out;
    float* xn    = out;                        // recon region doubles as xn scratch
    float* ids_f = out + (size_t)NB * DIN;     // 12582912
    float* rl    = out + (size_t)NB * DIN + (size_t)NB * 4;      // 12648448
    float* vl    = rl + 1;

    float* ws   = (float*)d_ws;
    float* h0   = ws;                           // 16384*512
    float* h1   = h0 + (size_t)NB * 512;        // 16384*256
    float* h2   = h1 + (size_t)NB * 256;        // 16384*128
    float* rbuf = h2 + (size_t)NB * 128;        // 16384*128
    float* qsum = rbuf + (size_t)NB * 128;      // 16384*128
    float* cbn  = qsum + (size_t)NB * 128;      // 4*8192
    int*   idxb = (int*)(cbn + 4 * 8192);       // 16384

    // strip-partial argmin buffers live in h0 (free between encoder and decoder)
    float* pbest = h0;                          // 2*16384 floats
    int*   pidx  = (int*)(h0 + 2 * (size_t)NB); // 2*16384 ints

    k_zero2<<<1, 64, 0, stream>>>(rl, vl);
    k_norm<<<(NB * DIN) / 256, 256, 0, stream>>>(x, emb_mean, emb_std, xn);
    k_cbnorm<<<(4 * 8192) / 4, 256, 0, stream>>>(cb, cbn);

    k_lin_relu_rms<512><<<NB / 32, 256, 0, stream>>>(xn, enc_w0, enc_b0, enc_g0, h0, 768);
    k_lin_relu_rms<256><<<NB / 32, 256, 0, stream>>>(h0, enc_w1, enc_b1, enc_g1, h1, 512);
    k_lin_relu_rms<128><<<NB / 32, 256, 0, stream>>>(h1, enc_w2, enc_b2, enc_g2, h2, 256);

    for (int q = 0; q < 4; q++) {
        const float* R = (q == 0) ? h2 : rbuf;
        const float* Eq = cb + (size_t)q * 8192 * 128;
        dim3 gq(NB / 64, 2);
        k_vq_argmin<<<gq, 256, 0, stream>>>(R, Eq, cbn + q * 8192, pbest, pidx);
        k_vq_reduce<<<NB / 256, 256, 0, stream>>>(pbest, pidx, idxb, ids_f + q);
        k_vq_update<<<(NB * 128) / 256, 256, 0, stream>>>(R, idxb, Eq, rbuf, qsum, vl, q == 0 ? 1 : 0);
    }

    k_lin_relu_rms<256><<<NB / 32, 256, 0, stream>>>(qsum, dec_w0, dec_b0, dec_g0, h1, 128);
    k_lin_relu_rms<512><<<NB / 32, 256, 0, stream>>>(h1, dec_w1, dec_b1, dec_g1, h0, 256);

    dim3 g2(NB / 64, DIN / 64);
    k_dec2<<<g2, 256, 0, stream>>>(h0, dec_w2, dec_b2, xn, rl);
}